// Round 1
// baseline (1101.324 us; speedup 1.0000x reference)
//
#include <hip/hip_runtime.h>
#include <math.h>

#define NN 100000
constexpr float MAXNORM_C = 0.996f;   // (1 - 4e-3)/sqrt(c), c=1
constexpr float MINNORM_C = 1e-15f;

// ---------- prep: transpose the 4 weight matrices into ws ----------
// wt[m][k][j] = W_m[j][k], m in {pos, pos_cc, neg, neg_cc}
__global__ void prep_transpose(const float* __restrict__ Wp, const float* __restrict__ Wpc,
                               const float* __restrict__ Wn, const float* __restrict__ Wnc,
                               float* __restrict__ wt) {
    int idx = blockIdx.x * 256 + threadIdx.x;   // 0..16383
    int m = idx >> 12;
    int k = (idx >> 6) & 63;
    int j = idx & 63;
    const float* W = (m == 0) ? Wp : (m == 1) ? Wpc : (m == 2) ? Wn : Wnc;
    wt[idx] = W[j * 64 + k];
}

__device__ inline float wave_sum64(float v) {
    #pragma unroll
    for (int m = 32; m >= 1; m >>= 1) v += __shfl_xor(v, m, 64);
    return v;
}

// ---------- prep: hyp_bias = proj(expmap0(b, c), c), plus its |.|^2 ----------
// hb layout: [hb_pos[64], y2_pos, hb_neg[64], y2_neg]  (65 floats per half)
__global__ void prep_bias(const float* __restrict__ bp, const float* __restrict__ bn,
                          float* __restrict__ hb) {
    int l = threadIdx.x;   // one wave
    #pragma unroll
    for (int h = 0; h < 2; ++h) {
        float u = (h ? bn : bp)[l];
        float norm = fmaxf(sqrtf(wave_sum64(u * u)), MINNORM_C);
        float s = tanhf(norm) / norm;          // sqrt_c = 1
        float v = s * u;
        float vn = fmaxf(sqrtf(wave_sum64(v * v)), MINNORM_C);
        if (vn > MAXNORM_C) v *= MAXNORM_C / vn;
        float y2 = wave_sum64(v * v);
        hb[h * 65 + l] = v;
        if (l == 0) hb[h * 65 + 64] = y2;
    }
}

// ---------- scatter: wave-per-edge atomic sum into d_out halves ----------
__global__ void scatter_kernel(const int* __restrict__ ei, int E,
                               const float* __restrict__ x,
                               float* __restrict__ out, float* __restrict__ cnt,
                               int halfoff) {
    int t = blockIdx.x * 256 + threadIdx.x;
    int e = t >> 6;
    int lane = threadIdx.x & 63;
    if (e >= E) return;
    int src = ei[e];          // row 0 of edge_index
    int dst = ei[E + e];      // row 1
    float v = x[src * 64 + lane];                       // coalesced 256B per wave
    atomicAdd(&out[dst * 128 + halfoff + lane], v);     // coalesced 256B atomic burst
    if (lane == 0) atomicAdd(&cnt[dst], 1.0f);
}

// ---------- per-lane hyperbolic linear: proj(mobius_matvec(W, v, c)) ----------
// vp points at this lane's 64-float input row; result left in mx[64] (registers).
// wtm is a transposed 64x64 matrix (uniform across wave -> scalar loads).
__device__ inline void hyp_mm_proj(const float* vp, float cinv,
                                   const float* __restrict__ wtm, float (&mx)[64]) {
    #pragma unroll
    for (int j = 0; j < 64; ++j) mx[j] = 0.f;
    float vn2 = 0.f;
    for (int k0 = 0; k0 < 64; k0 += 4) {        // dynamic loop: keeps I-cache small
        float4 a4 = *(const float4*)(vp + k0);
        float a0 = a4.x * cinv, a1 = a4.y * cinv, a2 = a4.z * cinv, a3 = a4.w * cinv;
        vn2 = fmaf(a0, a0, fmaf(a1, a1, fmaf(a2, a2, fmaf(a3, a3, vn2))));
        const float* w0 = wtm + k0 * 64;        // uniform address -> s_load
        #pragma unroll
        for (int j = 0; j < 64; ++j) {
            float m = mx[j];
            m = fmaf(a0, w0[j],        m);
            m = fmaf(a1, w0[64 + j],   m);
            m = fmaf(a2, w0[128 + j],  m);
            m = fmaf(a3, w0[192 + j],  m);
            mx[j] = m;
        }
    }
    float mn2 = 0.f;
    #pragma unroll
    for (int j = 0; j < 64; ++j) mn2 = fmaf(mx[j], mx[j], mn2);
    float xnorm = fmaxf(sqrtf(vn2), MINNORM_C);
    float mnorm = fmaxf(sqrtf(mn2), MINNORM_C);
    float z = fminf(xnorm, 1.0f - 1e-7f);                   // artanh clip (z >= 0)
    float art = 0.5f * logf((1.0f + z) / (1.0f - z));
    float t = tanhf(mnorm / xnorm * art);
    float scale = (mn2 == 0.f) ? 0.f : (t / mnorm);         // zero_mx branch
    #pragma unroll
    for (int j = 0; j < 64; ++j) mx[j] *= scale;
    float rn2 = 0.f;
    #pragma unroll
    for (int j = 0; j < 64; ++j) rn2 = fmaf(mx[j], mx[j], rn2);
    float rnorm = fmaxf(sqrtf(rn2), MINNORM_C);
    float f = (rnorm > MAXNORM_C) ? (MAXNORM_C / rnorm) : 1.0f;   // proj
    #pragma unroll
    for (int j = 0; j < 64; ++j) mx[j] *= f;
}

// ---------- finalize: lane-per-node, one half (pos/neg) per block ----------
__global__ __launch_bounds__(256) void finalize_kernel(
    const float* __restrict__ x,
    const float* __restrict__ wt,    // 4 transposed 64x64 matrices
    const float* __restrict__ hb,    // 2 x 65
    const float* __restrict__ cnt,   // 2 x NN
    float* __restrict__ out) {
    int half = blockIdx.x & 1;                      // uniform -> wt/hb scalar loads
    int group = (blockIdx.x >> 1) * 4 + (threadIdx.x >> 6);
    int lane = threadIdx.x & 63;
    int node = group * 64 + lane;
    bool valid = node < NN;
    int nc = valid ? node : NN - 1;

    const float* wtA = wt + half * 8192;            // W_pos / W_neg
    const float* wtB = wtA + 4096;                  // W_pos_cc / W_neg_cc
    const float* hbh = hb + half * 65;

    float cv = cnt[half * NN + nc];
    float cinv = 1.0f / fmaxf(cv, 1.0f);            // scatter_mean divisor

    // chain A: proj(mobius_matvec(W, agg))  (agg = out-half * cinv, in place)
    float resA[64];
    hyp_mm_proj(out + (size_t)nc * 128 + half * 64, cinv, wtA, resA);

    // chain B: proj(mobius_matvec(W_cc, x))
    float resB[64];
    hyp_mm_proj(x + (size_t)nc * 64, 1.0f, wtB, resB);

    // proj(mobius_add(resB, hyp_bias)), c=1
    float x2 = 0.f, xy = 0.f;
    #pragma unroll
    for (int j = 0; j < 64; ++j) {
        x2 = fmaf(resB[j], resB[j], x2);
        xy = fmaf(resB[j], hbh[j], xy);
    }
    float y2 = hbh[64];
    float A = 1.f + 2.f * xy + y2;
    float B = 1.f - x2;
    float den = 1.f + 2.f * xy + x2 * y2;
    float dinv = 1.f / fmaxf(den, MINNORM_C);
    float rn2 = 0.f;
    #pragma unroll
    for (int j = 0; j < 64; ++j) {
        float r = (A * resB[j] + B * hbh[j]) * dinv;
        resB[j] = r;
        rn2 = fmaf(r, r, rn2);
    }
    float rnorm = fmaxf(sqrtf(rn2), MINNORM_C);
    float f = (rnorm > MAXNORM_C) ? (MAXNORM_C / rnorm) : 1.0f;

    if (valid) {
        float* op = out + (size_t)node * 128 + half * 64;
        #pragma unroll
        for (int k0 = 0; k0 < 64; k0 += 4) {
            float4 s;
            s.x = resA[k0 + 0] + resB[k0 + 0] * f;
            s.y = resA[k0 + 1] + resB[k0 + 1] * f;
            s.z = resA[k0 + 2] + resB[k0 + 2] * f;
            s.w = resA[k0 + 3] + resB[k0 + 3] * f;
            *(float4*)(op + k0) = s;
        }
    }
}

extern "C" void kernel_launch(void* const* d_in, const int* in_sizes, int n_in,
                              void* d_out, int out_size, void* d_ws, size_t ws_size,
                              hipStream_t stream) {
    const float* x   = (const float*)d_in[0];
    const float* Wp  = (const float*)d_in[1];
    const float* Wpc = (const float*)d_in[2];
    const float* bp  = (const float*)d_in[3];
    const float* Wn  = (const float*)d_in[4];
    const float* Wnc = (const float*)d_in[5];
    const float* bn  = (const float*)d_in[6];
    const int* pei = (const int*)d_in[7];
    const int* nei = (const int*)d_in[8];
    float* out = (float*)d_out;
    float* ws  = (float*)d_ws;

    int E1 = in_sizes[7] / 2;
    int E2 = in_sizes[8] / 2;

    // ws layout (floats): cnt_pos[NN], cnt_neg[NN], hb[130], pad, wt[4*4096]
    float* cnt = ws;
    float* hb  = ws + 2 * NN;
    float* wt  = ws + 2 * NN + 192;

    // zero accumulators (d_out is re-poisoned to 0xAA before every launch)
    hipMemsetAsync(out, 0, (size_t)out_size * sizeof(float), stream);
    hipMemsetAsync(cnt, 0, (size_t)(2 * NN) * sizeof(float), stream);

    prep_transpose<<<64, 256, 0, stream>>>(Wp, Wpc, Wn, Wnc, wt);
    prep_bias<<<1, 64, 0, stream>>>(bp, bn, hb);

    scatter_kernel<<<(E1 * 64 + 255) / 256, 256, 0, stream>>>(pei, E1, x, out, cnt, 0);
    scatter_kernel<<<(E2 * 64 + 255) / 256, 256, 0, stream>>>(nei, E2, x, out, cnt + NN, 64);

    int groups = (NN + 63) / 64;                 // 1563
    int blocks = 2 * ((groups + 3) / 4);         // half from blockIdx -> uniform
    finalize_kernel<<<blocks, 256, 0, stream>>>(x, wt, hb, cnt, out);
}

// Round 2
// 784.787 us; speedup vs baseline: 1.4033x; 1.4033x over previous
//
#include <hip/hip_runtime.h>
#include <math.h>

#define NN 100000
constexpr float MAXNORM_C = 0.996f;   // (1 - 4e-3)/sqrt(c), c=1
constexpr float MINNORM_C = 1e-15f;

// ---------- prep: transpose the 4 weight matrices into ws ----------
__global__ void prep_transpose(const float* __restrict__ Wp, const float* __restrict__ Wpc,
                               const float* __restrict__ Wn, const float* __restrict__ Wnc,
                               float* __restrict__ wt) {
    int idx = blockIdx.x * 256 + threadIdx.x;   // 0..16383
    int m = idx >> 12;
    int k = (idx >> 6) & 63;
    int j = idx & 63;
    const float* W = (m == 0) ? Wp : (m == 1) ? Wpc : (m == 2) ? Wn : Wnc;
    wt[idx] = W[j * 64 + k];
}

__device__ inline float wave_sum64(float v) {
    #pragma unroll
    for (int m = 32; m >= 1; m >>= 1) v += __shfl_xor(v, m, 64);
    return v;
}

// ---------- prep: hyp_bias = proj(expmap0(b, c), c), plus its |.|^2 ----------
__global__ void prep_bias(const float* __restrict__ bp, const float* __restrict__ bn,
                          float* __restrict__ hb) {
    int l = threadIdx.x;   // one wave
    #pragma unroll
    for (int h = 0; h < 2; ++h) {
        float u = (h ? bn : bp)[l];
        float norm = fmaxf(sqrtf(wave_sum64(u * u)), MINNORM_C);
        float s = tanhf(norm) / norm;          // sqrt_c = 1
        float v = s * u;
        float vn = fmaxf(sqrtf(wave_sum64(v * v)), MINNORM_C);
        if (vn > MAXNORM_C) v *= MAXNORM_C / vn;
        float y2 = wave_sum64(v * v);
        hb[h * 65 + l] = v;
        if (l == 0) hb[h * 65 + 64] = y2;
    }
}

// ---------- CSR build ----------
// count: one thread per edge (both halves), int atomic increment of cnt[half*NN+dst]
__global__ void count_kernel(const int* __restrict__ pei, int E1,
                             const int* __restrict__ nei, int E2,
                             int* __restrict__ cnt) {
    int idx = blockIdx.x * 256 + threadIdx.x;
    int tot = E1 + E2;
    if (idx >= tot) return;
    int half = idx >= E1;
    int e = idx - (half ? E1 : 0);
    const int* ei = half ? nei : pei;
    int E = half ? E2 : E1;
    int dst = ei[E + e];
    atomicAdd(&cnt[half * NN + dst], 1);
}

// scan1: 1024 items per block (256 thr x 4), exclusive scan within block + block sum
__global__ void scan1_kernel(const int* __restrict__ cnt, int* __restrict__ offs,
                             int* __restrict__ bsum, int n) {
    __shared__ int tmp[256];
    int tid = threadIdx.x;
    int base = blockIdx.x * 1024 + tid * 4;
    int items[4];
    int s = 0;
    #pragma unroll
    for (int i = 0; i < 4; ++i) {
        items[i] = (base + i < n) ? cnt[base + i] : 0;
        s += items[i];
    }
    tmp[tid] = s;
    __syncthreads();
    for (int off = 1; off < 256; off <<= 1) {
        int v = (tid >= off) ? tmp[tid - off] : 0;
        __syncthreads();
        tmp[tid] += v;
        __syncthreads();
    }
    int run = tmp[tid] - s;   // exclusive prefix of this thread's chunk
    if (tid == 255) bsum[blockIdx.x] = tmp[255];
    #pragma unroll
    for (int i = 0; i < 4; ++i) {
        if (base + i < n) offs[base + i] = run;
        run += items[i];
    }
}

// scan2: exclusive scan of block sums (nb <= 256), single block
__global__ void scan2_kernel(int* __restrict__ bsum, int nb) {
    __shared__ int tmp[256];
    int tid = threadIdx.x;
    int s = (tid < nb) ? bsum[tid] : 0;
    tmp[tid] = s;
    __syncthreads();
    for (int off = 1; off < 256; off <<= 1) {
        int v = (tid >= off) ? tmp[tid - off] : 0;
        __syncthreads();
        tmp[tid] += v;
        __syncthreads();
    }
    if (tid < nb) bsum[tid] = tmp[tid] - s;   // exclusive
}

// scan3: add block offset; also write cursor copy
__global__ void scan3_kernel(int* __restrict__ offs, int* __restrict__ cursor,
                             const int* __restrict__ bsum, int n) {
    int idx = blockIdx.x * 256 + threadIdx.x;
    if (idx >= n) return;
    int b = idx >> 10;
    int v = offs[idx] + bsum[b];
    offs[idx] = v;
    cursor[idx] = v;
}

// fill: one thread per edge; claim slot via cursor atomic, write src
__global__ void fill_kernel(const int* __restrict__ pei, int E1,
                            const int* __restrict__ nei, int E2,
                            int* __restrict__ cursor, int* __restrict__ esrc) {
    int idx = blockIdx.x * 256 + threadIdx.x;
    int tot = E1 + E2;
    if (idx >= tot) return;
    int half = idx >= E1;
    int e = idx - (half ? E1 : 0);
    const int* ei = half ? nei : pei;
    int E = half ? E2 : E1;
    int src = ei[e];
    int dst = ei[E + e];
    int pos = atomicAdd(&cursor[half * NN + dst], 1);
    esrc[pos] = src;
}

// gather: wave per node-half, lane = feature; writes MEAN into out half
__global__ __launch_bounds__(256) void gather_kernel(
    const int* __restrict__ offs, const int* __restrict__ cnt,
    const int* __restrict__ esrc, const float* __restrict__ x,
    float* __restrict__ out) {
    int wid = (blockIdx.x * 256 + threadIdx.x) >> 6;   // node-half id, 0..2NN
    int lane = threadIdx.x & 63;
    if (wid >= 2 * NN) return;
    int half = wid >= NN;
    int node = wid - (half ? NN : 0);
    int start = offs[wid];
    int deg = cnt[wid];
    float acc = 0.f;
    for (int b = 0; b < deg; b += 64) {
        int n = min(64, deg - b);
        int s_l = (b + lane < deg) ? esrc[start + b + lane] : 0;
        int i = 0;
        for (; i + 4 <= n; i += 4) {
            int a0 = __shfl(s_l, i, 64), a1 = __shfl(s_l, i + 1, 64);
            int a2 = __shfl(s_l, i + 2, 64), a3 = __shfl(s_l, i + 3, 64);
            float v0 = x[a0 * 64 + lane], v1 = x[a1 * 64 + lane];
            float v2 = x[a2 * 64 + lane], v3 = x[a3 * 64 + lane];
            acc += (v0 + v1) + (v2 + v3);
        }
        for (; i < n; ++i) acc += x[__shfl(s_l, i, 64) * 64 + lane];
    }
    float m = acc / fmaxf((float)deg, 1.f);
    out[(size_t)node * 128 + half * 64 + lane] = m;
}

// ---------- per-lane hyperbolic linear: proj(mobius_matvec(W, v, c)) ----------
__device__ inline void hyp_mm_proj(const float* vp, float cinv,
                                   const float* __restrict__ wtm, float (&mx)[64]) {
    #pragma unroll
    for (int j = 0; j < 64; ++j) mx[j] = 0.f;
    float vn2 = 0.f;
    for (int k0 = 0; k0 < 64; k0 += 4) {
        float4 a4 = *(const float4*)(vp + k0);
        float a0 = a4.x * cinv, a1 = a4.y * cinv, a2 = a4.z * cinv, a3 = a4.w * cinv;
        vn2 = fmaf(a0, a0, fmaf(a1, a1, fmaf(a2, a2, fmaf(a3, a3, vn2))));
        const float* w0 = wtm + k0 * 64;        // uniform address -> s_load
        #pragma unroll
        for (int j = 0; j < 64; ++j) {
            float m = mx[j];
            m = fmaf(a0, w0[j],        m);
            m = fmaf(a1, w0[64 + j],   m);
            m = fmaf(a2, w0[128 + j],  m);
            m = fmaf(a3, w0[192 + j],  m);
            mx[j] = m;
        }
    }
    float mn2 = 0.f;
    #pragma unroll
    for (int j = 0; j < 64; ++j) mn2 = fmaf(mx[j], mx[j], mn2);
    float xnorm = fmaxf(sqrtf(vn2), MINNORM_C);
    float mnorm = fmaxf(sqrtf(mn2), MINNORM_C);
    float z = fminf(xnorm, 1.0f - 1e-7f);                   // artanh clip
    float art = 0.5f * logf((1.0f + z) / (1.0f - z));
    float t = tanhf(mnorm / xnorm * art);
    float scale = (mn2 == 0.f) ? 0.f : (t / mnorm);         // zero_mx branch
    #pragma unroll
    for (int j = 0; j < 64; ++j) mx[j] *= scale;
    float rn2 = 0.f;
    #pragma unroll
    for (int j = 0; j < 64; ++j) rn2 = fmaf(mx[j], mx[j], rn2);
    float rnorm = fmaxf(sqrtf(rn2), MINNORM_C);
    float f = (rnorm > MAXNORM_C) ? (MAXNORM_C / rnorm) : 1.0f;   // proj
    #pragma unroll
    for (int j = 0; j < 64; ++j) mx[j] *= f;
}

// ---------- finalize: lane-per-node, one half per block (agg pre-divided) ----------
__global__ __launch_bounds__(256) void finalize_kernel(
    const float* __restrict__ x,
    const float* __restrict__ wt,    // 4 transposed 64x64 matrices
    const float* __restrict__ hb,    // 2 x 65
    float* __restrict__ out) {
    int half = blockIdx.x & 1;                      // uniform -> scalar weight loads
    int group = (blockIdx.x >> 1) * 4 + (threadIdx.x >> 6);
    int lane = threadIdx.x & 63;
    int node = group * 64 + lane;
    bool valid = node < NN;
    int nc = valid ? node : NN - 1;

    const float* wtA = wt + half * 8192;            // W_pos / W_neg
    const float* wtB = wtA + 4096;                  // W_pos_cc / W_neg_cc
    const float* hbh = hb + half * 65;

    // chain A: proj(mobius_matvec(W, agg))  (agg already the mean, in out-half)
    float resA[64];
    hyp_mm_proj(out + (size_t)nc * 128 + half * 64, 1.0f, wtA, resA);

    // chain B: proj(mobius_matvec(W_cc, x))
    float resB[64];
    hyp_mm_proj(x + (size_t)nc * 64, 1.0f, wtB, resB);

    // proj(mobius_add(resB, hyp_bias)), c=1
    float x2 = 0.f, xy = 0.f;
    #pragma unroll
    for (int j = 0; j < 64; ++j) {
        x2 = fmaf(resB[j], resB[j], x2);
        xy = fmaf(resB[j], hbh[j], xy);
    }
    float y2 = hbh[64];
    float A = 1.f + 2.f * xy + y2;
    float B = 1.f - x2;
    float den = 1.f + 2.f * xy + x2 * y2;
    float dinv = 1.f / fmaxf(den, MINNORM_C);
    float rn2 = 0.f;
    #pragma unroll
    for (int j = 0; j < 64; ++j) {
        float r = (A * resB[j] + B * hbh[j]) * dinv;
        resB[j] = r;
        rn2 = fmaf(r, r, rn2);
    }
    float rnorm = fmaxf(sqrtf(rn2), MINNORM_C);
    float f = (rnorm > MAXNORM_C) ? (MAXNORM_C / rnorm) : 1.0f;

    if (valid) {
        float* op = out + (size_t)node * 128 + half * 64;
        #pragma unroll
        for (int k0 = 0; k0 < 64; k0 += 4) {
            float4 s;
            s.x = resA[k0 + 0] + resB[k0 + 0] * f;
            s.y = resA[k0 + 1] + resB[k0 + 1] * f;
            s.z = resA[k0 + 2] + resB[k0 + 2] * f;
            s.w = resA[k0 + 3] + resB[k0 + 3] * f;
            *(float4*)(op + k0) = s;
        }
    }
}

extern "C" void kernel_launch(void* const* d_in, const int* in_sizes, int n_in,
                              void* d_out, int out_size, void* d_ws, size_t ws_size,
                              hipStream_t stream) {
    const float* x   = (const float*)d_in[0];
    const float* Wp  = (const float*)d_in[1];
    const float* Wpc = (const float*)d_in[2];
    const float* bp  = (const float*)d_in[3];
    const float* Wn  = (const float*)d_in[4];
    const float* Wnc = (const float*)d_in[5];
    const float* bn  = (const float*)d_in[6];
    const int* pei = (const int*)d_in[7];
    const int* nei = (const int*)d_in[8];
    float* out = (float*)d_out;

    int E1 = in_sizes[7] / 2;
    int E2 = in_sizes[8] / 2;
    int tot = E1 + E2;
    int n2 = 2 * NN;

    // ws layout (4-byte units):
    //   cnt[2NN] | offs[2NN] | cursor[2NN] | bsum[256] | hb[130+pad 192] | wt[16384] | esrc[E1+E2]
    int*   cnt    = (int*)d_ws;
    int*   offs   = cnt + n2;
    int*   cursor = offs + n2;
    int*   bsum   = cursor + n2;
    float* hb     = (float*)(bsum + 256);
    float* wt     = hb + 192;
    int*   esrc   = (int*)(wt + 16384);

    hipMemsetAsync(cnt, 0, (size_t)n2 * sizeof(int), stream);

    prep_transpose<<<64, 256, 0, stream>>>(Wp, Wpc, Wn, Wnc, wt);
    prep_bias<<<1, 64, 0, stream>>>(bp, bn, hb);

    count_kernel<<<(tot + 255) / 256, 256, 0, stream>>>(pei, E1, nei, E2, cnt);

    int nb = (n2 + 1023) / 1024;   // 196
    scan1_kernel<<<nb, 256, 0, stream>>>(cnt, offs, bsum, n2);
    scan2_kernel<<<1, 256, 0, stream>>>(bsum, nb);
    scan3_kernel<<<(n2 + 255) / 256, 256, 0, stream>>>(offs, cursor, bsum, n2);

    fill_kernel<<<(tot + 255) / 256, 256, 0, stream>>>(pei, E1, nei, E2, cursor, esrc);

    gather_kernel<<<(n2 * 64 + 255) / 256, 256, 0, stream>>>(offs, cnt, esrc, x, out);

    int groups = (NN + 63) / 64;                 // 1563
    int blocks = 2 * ((groups + 3) / 4);
    finalize_kernel<<<blocks, 256, 0, stream>>>(x, wt, hb, out);
}